// Round 14
// baseline (100.731 us; speedup 1.0000x reference)
//
#include <hip/hip_runtime.h>

#define NROB 32
#define SEQ 12
#define LOBS 52
#define HID 256
#define LOUT 2
#define KIN 624            // SEQ*LOBS
#define SPB 8              // samples per chunk
#define NSD 24             // SEQ*LOUT
#define NCH 160            // chunk slots (>= max 156)
#define NBLK 320           // NCH x 2 K-halves
#define SLOTS 20

// static LDS (floats): x0 [8][624] | P [4][8][256] | x1 [8][256]
// x2 aliases x0; Wo tile S aliases P.
#define OFF_P 4992
#define OFF_X1 13184
#define ARENA_F 15232      // 60928 B -> 2 blocks/CU (160 KB LDS)

// ws: flags int[NCH][4] (pad to 4096 floats), then partials [NCH][2][2048] fl
#define WS_PART 4096

__device__ __forceinline__ void fma4(float4& a, const float4 w, const float s) {
  a.x = fmaf(w.x, s, a.x);
  a.y = fmaf(w.y, s, a.y);
  a.z = fmaf(w.z, s, a.z);
  a.w = fmaf(w.w, s, a.w);
}

// R13-verified stream core: ROWS weight rows (stride HID, float4/lane = 1KB
// coalesced) vs 8 samples (LDS b128 broadcast). A/B 4-row register dbuf.
template <int ROWS, int XS>
__device__ __forceinline__ void stream8(const float* __restrict__ wp,
                                        const float* xb, float4* acc) {
  static_assert(ROWS % 8 == 0, "ROWS multiple of 8");
  constexpr int G = ROWS / 4;  // even
  float4 A[4], B[4];
#pragma unroll
  for (int j = 0; j < 4; ++j) A[j] = *(const float4*)(wp + j * HID);
#pragma unroll
  for (int j = 0; j < 4; ++j) B[j] = *(const float4*)(wp + (4 + j) * HID);
#pragma unroll
  for (int g = 0; g < G; g += 2) {
    const int k = g * 4;
#pragma unroll
    for (int m = 0; m < SPB; ++m) {
      const float4 x = *(const float4*)(xb + m * XS + k);
      fma4(acc[m], A[0], x.x);
      fma4(acc[m], A[1], x.y);
      fma4(acc[m], A[2], x.z);
      fma4(acc[m], A[3], x.w);
    }
    if (g + 2 < G) {
#pragma unroll
      for (int j = 0; j < 4; ++j)
        A[j] = *(const float4*)(wp + (size_t)(k + 8 + j) * HID);
    }
#pragma unroll
    for (int m = 0; m < SPB; ++m) {
      const float4 x = *(const float4*)(xb + m * XS + k + 4);
      fma4(acc[m], B[0], x.x);
      fma4(acc[m], B[1], x.y);
      fma4(acc[m], B[2], x.z);
      fma4(acc[m], B[3], x.w);
    }
    if (g + 3 < G) {
#pragma unroll
      for (int j = 0; j < 4; ++j)
        B[j] = *(const float4*)(wp + (size_t)(k + 12 + j) * HID);
    }
  }
}

__global__ void k_init(int* flags) {
  const int i = blockIdx.x * 256 + threadIdx.x;
  if (i < NCH * 4) flags[i] = 0;
}

__global__ __launch_bounds__(512, 4) void k_fused(
    const float* __restrict__ obs, const int* __restrict__ mask,
    const int* __restrict__ ids, const float* __restrict__ Wi,
    const float* __restrict__ bi, const float* __restrict__ W1,
    const float* __restrict__ b1, const float* __restrict__ W2,
    const float* __restrict__ b2, const float* __restrict__ W3,
    const float* __restrict__ b3, const float* __restrict__ Wo,
    const float* __restrict__ bo, float* __restrict__ out,
    int* __restrict__ flags, float* __restrict__ parts) {
  __shared__ int s_cnt[NROB];
  __shared__ int s_wc[8];
  __shared__ int s_h0;
  __shared__ int s_bm[SPB], s_vm[SPB], s_mb[SPB];
  __shared__ float s_ind[SPB][SEQ];
  __shared__ __align__(16) float sm[ARENA_F];
  float* x0 = sm;
  float* P = sm + OFF_P;
  float* x1 = sm + OFF_X1;
  float* x2 = sm;  // aliases dead x0

  const int t = threadIdx.x;
  const int bx = blockIdx.x;
  // pair decomposition: chunk c (0..159), K-half h; partner = bx^8 (same XCD)
  const int c = ((bx >> 4) << 3) | (bx & 7);
  const int h = (bx >> 3) & 1;

  // ---- phase 0a: histogram ----
  if (t < NROB) s_cnt[t] = 0;
  if (t < SPB) s_bm[t] = 0;
  __syncthreads();
  const int id0 = ids[t];
  const int id1 = ids[t + 512];
  atomicAdd(&s_cnt[id0], 1);
  atomicAdd(&s_cnt[id1], 1);
  __syncthreads();

  // ---- phase 0b: deterministic chunk->robot mapping (XCD-swizzled by c&7) ----
  int myr = -1, mybase = 0;
  {
    int maxbucket = 0;
    for (int x = 0; x < 8; ++x) {
      int bsum = 0;
      for (int r = x; r < NROB; r += 8) bsum += (s_cnt[r] + SPB - 1) >> 3;
      maxbucket = max(maxbucket, bsum);
    }
    if (maxbucket <= SLOTS) {
      const int myxcd = c & 7, myslot = c >> 3;
      int slot = 0;
      for (int r = myxcd; r < NROB; r += 8) {
        const int nch = (s_cnt[r] + SPB - 1) >> 3;
        if (myr < 0 && myslot >= slot && myslot < slot + nch) {
          myr = r;
          mybase = (myslot - slot) * SPB;
        }
        slot += nch;
      }
    } else {
      int ch = 0;
      for (int r = 0; r < NROB; ++r) {
        const int nch = (s_cnt[r] + SPB - 1) >> 3;
        if (myr < 0 && c >= ch && c < ch + nch) {
          myr = r;
          mybase = (c - ch) * SPB;
        }
        ch += nch;
      }
    }
  }
  if (myr < 0) return;  // uniform; both halves of pair exit together
  const int mycnt = s_cnt[myr];

  // ---- phase 0c: stable sample ranks via ballot scan (two halves) ----
  {
    const int wv = t >> 6;
    const unsigned lane = t & 63;
    const unsigned long long m0 = __ballot(id0 == myr);
    const unsigned long long m1 = __ballot(id1 == myr);
    if (lane == 0) s_wc[wv] = __popcll(m0);
    __syncthreads();
    const unsigned long long below = (1ull << lane) - 1ull;
    int pre0 = 0;
    for (int i = 0; i < wv; ++i) pre0 += s_wc[i];
    if (id0 == myr) {
      const int j = pre0 + __popcll(m0 & below) - mybase;
      if (j >= 0 && j < SPB) s_bm[j] = t;
    }
    __syncthreads();
    if (lane == 0) s_wc[wv] = __popcll(m1);
    if (t == 0) s_h0 = 0;
    __syncthreads();
    int pre1 = 0;
    for (int i = 0; i < wv; ++i) pre1 += s_wc[i];
    if (lane == 0) atomicAdd(&s_h0, __popcll(m0));
    __syncthreads();
    if (id1 == myr) {
      const int j = s_h0 + pre1 + __popcll(m1 & below) - mybase;
      if (j >= 0 && j < SPB) s_bm[j] = t + 512;
    }
    __syncthreads();
  }
  if (t < SPB) {
    const int v = (mybase + t) < mycnt;
    s_vm[t] = v;
    int mb = 0xFFF;
    if (v) {
      mb = 0;
      const int b = s_bm[t];
      for (int s = 0; s < SEQ; ++s) mb |= (mask[b * SEQ + s] != 0) << s;
    }
    s_mb[t] = mb;
  }
  __syncthreads();
  if (t < SPB * SEQ) {
    const int m = t / SEQ, s = t - m * SEQ;
    s_ind[m][s] = ((s_mb[m] >> s) & 1) ? 0.f : 1.f;
  }
  for (int q = t; q < SPB * (KIN / 4); q += 512) {
    const int m = q / 156, f4 = q - m * 156;
    const int s = f4 / 13;
    float4 v = {0.f, 0.f, 0.f, 0.f};
    if (!((s_mb[m] >> s) & 1))
      v = *(const float4*)(obs + (size_t)s_bm[m] * KIN + f4 * 4);
    *(float4*)&x0[m * KIN + f4 * 4] = v;
  }
  __syncthreads();

  const int w = t >> 6, lane = t & 63;
  float* Pp = P + (w >> 1) * (SPB * HID) + lane * 4;
  float* pme = parts + WS_PART + (size_t)(c * 2 + h) * 2048;
  float* pyou = parts + WS_PART + (size_t)(c * 2 + (1 - h)) * 2048;

#define REDUCE_P()                                                       \
  if ((w & 1) == 0) {                                                    \
    _Pragma("unroll") for (int m = 0; m < SPB; ++m)                      \
        *(float4*)(Pp + m * HID) = acc[m];                               \
  }                                                                      \
  __syncthreads();                                                       \
  if (w & 1) {                                                           \
    _Pragma("unroll") for (int m = 0; m < SPB; ++m) {                    \
      float4 cc = *(const float4*)(Pp + m * HID);                        \
      cc.x += acc[m].x;                                                  \
      cc.y += acc[m].y;                                                  \
      cc.z += acc[m].z;                                                  \
      cc.w += acc[m].w;                                                  \
      *(float4*)(Pp + m * HID) = cc;                                     \
    }                                                                    \
  }                                                                      \
  __syncthreads();

#define EXCHANGE(Lidx, TMP)                                              \
  {                                                                      \
    const int m = t >> 6, c4 = (t & 63) * 4;                             \
    const float4 p0 = *(const float4*)&P[(0 * SPB + m) * HID + c4];      \
    const float4 p1 = *(const float4*)&P[(1 * SPB + m) * HID + c4];     \
    const float4 p2 = *(const float4*)&P[(2 * SPB + m) * HID + c4];     \
    const float4 p3 = *(const float4*)&P[(3 * SPB + m) * HID + c4];     \
    float4 a = {p0.x + p1.x + p2.x + p3.x, p0.y + p1.y + p2.y + p3.y,   \
                p0.z + p1.z + p2.z + p3.z, p0.w + p1.w + p2.w + p3.w};  \
    *(float4*)&pme[m * HID + c4] = a;                                    \
    *(float4*)&TMP[m * HID + c4] = a;                                    \
  }                                                                      \
  __syncthreads();                                                       \
  if (t == 0) {                                                          \
    __hip_atomic_fetch_add(&flags[c * 4 + Lidx], 1, __ATOMIC_RELEASE,   \
                           __HIP_MEMORY_SCOPE_AGENT);                    \
    while (__hip_atomic_load(&flags[c * 4 + Lidx], __ATOMIC_ACQUIRE,    \
                             __HIP_MEMORY_SCOPE_AGENT) < 2)             \
      __builtin_amdgcn_s_sleep(2);                                       \
  }                                                                      \
  __syncthreads();

  // ---- input layer: K-half h = rows [h*312, h*312+312), segs 7x40 + 32 ----
  {
    float4 acc[SPB];
#pragma unroll
    for (int m = 0; m < SPB; ++m) acc[m] = {0.f, 0.f, 0.f, 0.f};
    const float* Wr =
        Wi + ((size_t)myr * KIN + h * 312 + w * 40) * HID + lane * 4;
    const float* xb = x0 + h * 312 + w * 40;
    if (w < 7)
      stream8<40, KIN>(Wr, xb, acc);
    else
      stream8<32, KIN>(Wr, xb, acc);
    REDUCE_P()
    EXCHANGE(0, x1)
    {  // combine + bias-fold + relu -> x1
      const int m = t >> 6, c4 = (t & 63) * 4;
      float4 a = *(const float4*)&x1[m * HID + c4];
      const float4 b = *(const float4*)&pyou[m * HID + c4];
      a.x += b.x;
      a.y += b.y;
      a.z += b.z;
      a.w += b.w;
      const float* br = bi + (size_t)myr * SEQ * HID + c4;
#pragma unroll
      for (int s = 0; s < SEQ; ++s) {
        const float4 b4 = *(const float4*)(br + s * HID);
        const float f = s_ind[m][s];
        a.x = fmaf(b4.x, f, a.x);
        a.y = fmaf(b4.y, f, a.y);
        a.z = fmaf(b4.z, f, a.z);
        a.w = fmaf(b4.w, f, a.w);
      }
      float4 o = {fmaxf(a.x, 0.f), fmaxf(a.y, 0.f), fmaxf(a.z, 0.f),
                  fmaxf(a.w, 0.f)};
      *(float4*)&x1[m * HID + c4] = o;
    }
    __syncthreads();
  }

  // ---- hidden layers: K-half = rows [h*128, +128), 8 segs x 16 rows ----
  const float* Ws[3] = {W1, W2, W3};
  const float* bs[3] = {b1, b2, b3};
#pragma unroll
  for (int L = 0; L < 3; ++L) {
    const float* Xin = (L & 1) ? x2 : x1;
    float* Xout = (L & 1) ? x1 : x2;
    float4 acc[SPB];
#pragma unroll
    for (int m = 0; m < SPB; ++m) acc[m] = {0.f, 0.f, 0.f, 0.f};
    const float* Wr =
        Ws[L] + ((size_t)myr * HID + h * 128 + w * 16) * HID + lane * 4;
    stream8<16, HID>(Wr, Xin + h * 128 + w * 16, acc);
    REDUCE_P()
    EXCHANGE(L + 1, Xout)
    {
      const int m = t >> 6, c4 = (t & 63) * 4;
      float4 a = *(const float4*)&Xout[m * HID + c4];
      const float4 b = *(const float4*)&pyou[m * HID + c4];
      const float4 bv = *(const float4*)(bs[L] + (size_t)myr * HID + c4);
      float4 o = {fmaxf(a.x + b.x + bv.x, 0.f), fmaxf(a.y + b.y + bv.y, 0.f),
                  fmaxf(a.z + b.z + bv.z, 0.f), fmaxf(a.w + b.w + bv.w, 0.f)};
      *(float4*)&Xout[m * HID + c4] = o;
    }
    __syncthreads();
  }
  // final activations in x2

  // ---- output: half of sd-space each, no exchange ----
  float* S = P;  // 256*13 fl, P dead
  {
    const float* Wop = Wo + ((size_t)myr * SEQ + h * 6) * HID * LOUT;
    for (int q = t; q < (6 * HID * LOUT) / 4; q += 512) {
      const float4 v = *(const float4*)(Wop + q * 4);
      const int flat = q * 4;
      const int sl = flat >> 9;         // local s (0..5)
      const int k = (flat & 511) >> 1;  // d-pairs in float4
      S[(k + 0) * 13 + sl * 2 + 0] = v.x;
      S[(k + 0) * 13 + sl * 2 + 1] = v.y;
      S[(k + 1) * 13 + sl * 2 + 0] = v.z;
      S[(k + 1) * 13 + sl * 2 + 1] = v.w;
    }
  }
  __syncthreads();
  if (t < SPB * 12) {  // 96 threads: (sample, local sd)
    const int m = t / 12, j = t - m * 12;
    const int sd = h * 12 + j;
    float a = bo[(size_t)myr * NSD + sd];
    const float* xp = x2 + m * HID;
#pragma unroll 8
    for (int k = 0; k < HID; ++k) a = fmaf(xp[k], S[k * 13 + j], a);
    if (s_vm[m]) out[(size_t)s_bm[m] * NSD + sd] = a;
  }
}

extern "C" void kernel_launch(void* const* d_in, const int* in_sizes, int n_in,
                              void* d_out, int out_size, void* d_ws, size_t ws_size,
                              hipStream_t stream) {
  const float* obs = (const float*)d_in[0];
  const int* mask = (const int*)d_in[1];
  const int* ids = (const int*)d_in[2];
  const float* Wi = (const float*)d_in[3];
  const float* bi = (const float*)d_in[4];
  const float* W1 = (const float*)d_in[5];
  const float* b1 = (const float*)d_in[6];
  const float* W2 = (const float*)d_in[7];
  const float* b2 = (const float*)d_in[8];
  const float* W3 = (const float*)d_in[9];
  const float* b3 = (const float*)d_in[10];
  const float* Wo = (const float*)d_in[11];
  const float* bo = (const float*)d_in[12];
  float* out = (float*)d_out;
  int* flags = (int*)d_ws;
  float* parts = (float*)d_ws;

  hipLaunchKernelGGL(k_init, dim3(3), dim3(256), 0, stream, flags);
  hipLaunchKernelGGL(k_fused, dim3(NBLK), dim3(512), 0, stream, obs, mask,
                     ids, Wi, bi, W1, b1, W2, b2, W3, b3, Wo, bo, out, flags,
                     parts);
}